// Round 2
// baseline (3856.740 us; speedup 1.0000x reference)
//
#include <hip/hip_runtime.h>
#include <math.h>

#define B_ 8
#define L_ 512
#define DV_ 512
#define DM_ 512
#define PL_ 96
#define EL_ 3
#define DS_ 16
#define DC_ 4
#define DI_ 1024
#define DTR_ 32
#define S_ 512

typedef float f32x4 __attribute__((ext_vector_type(4)));
typedef short bf16x8 __attribute__((ext_vector_type(8)));

__device__ __forceinline__ float bf2f(short s) {
  unsigned u = ((unsigned)(unsigned short)s) << 16;
  return __builtin_bit_cast(float, u);
}
__device__ __forceinline__ short f2bf(float f) {
  unsigned u = __builtin_bit_cast(unsigned, f);
  u = u + 0x7FFFu + ((u >> 16) & 1u);   // RNE
  return (short)(u >> 16);
}

// ---------------------------------------------------------------------------
// Instance-norm statistics over the time axis (L) of x (B,L,DV) fp32.
// ---------------------------------------------------------------------------
__global__ __launch_bounds__(256)
void stats_k(const float* __restrict__ x, float* __restrict__ means,
             float* __restrict__ stdev, float* __restrict__ rstd,
             float* __restrict__ xlast)
{
  int d = blockIdx.x * 256 + threadIdx.x;       // 0..511
  int b = blockIdx.y;
  const float* xp = x + (size_t)b * L_ * DV_ + d;
  float s = 0.f, ss = 0.f;
  for (int l = 0; l < L_; l++) {
    float v = xp[(size_t)l * DV_];
    s += v; ss += v * v;
  }
  float mu = s / (float)L_;
  float var = ss / (float)L_ - mu * mu;
  float sd = sqrtf(var + 1e-5f);
  float rs = 1.f / sd;
  int idx = b * DV_ + d;
  means[idx] = mu; stdev[idx] = sd; rstd[idx] = rs;
  xlast[idx] = (xp[(size_t)(L_ - 1) * DV_] - mu) * rs;
}

// ---------------------------------------------------------------------------
// Normalize + transpose: xnT[b,d,l] = (x[b,l,d]-mu[b,d])*rstd[b,d]  (bf16)
// 64x64 LDS tile per block.
// ---------------------------------------------------------------------------
__global__ __launch_bounds__(256)
void tnorm_k(const float* __restrict__ x, const float* __restrict__ means,
             const float* __restrict__ rstd, short* __restrict__ xnT)
{
  __shared__ float tile[64][65];
  const int t = threadIdx.x;
  const int j = t & 63;
  const int i0 = t >> 6;                 // 0..3
  const int bz = blockIdx.z;
  const int l0 = blockIdx.y << 6;
  const int d0 = blockIdx.x << 6;
  const float* xp = x + ((size_t)bz * L_ + l0) * DV_ + d0;
  #pragma unroll
  for (int i = i0; i < 64; i += 4) tile[i][j] = xp[(size_t)i * DV_ + j];
  __syncthreads();
  short* op = xnT + ((size_t)bz * DV_ + d0) * L_ + l0;
  const int sb = bz * DV_ + d0;
  #pragma unroll
  for (int i = i0; i < 64; i += 4) {
    float mu = means[sb + i];
    float rs = rstd[sb + i];
    op[(size_t)i * L_ + j] = f2bf((tile[j][i] - mu) * rs);
  }
}

// ---------------------------------------------------------------------------
// LayerNorm over last dim (512) of fp32 h -> bf16 out.  One block per row.
// ---------------------------------------------------------------------------
__global__ __launch_bounds__(256)
void ln_k(const float* __restrict__ X, const float* __restrict__ g,
          const float* __restrict__ b, short* __restrict__ Y)
{
  int row = blockIdx.x;
  const float* x = X + (size_t)row * DM_;
  int t = threadIdx.x;
  float v0 = x[t], v1 = x[t + 256];
  float s = v0 + v1, ss = v0 * v0 + v1 * v1;
  #pragma unroll
  for (int o = 1; o < 64; o <<= 1) { s += __shfl_xor(s, o); ss += __shfl_xor(ss, o); }
  __shared__ float sb[8];
  int wave = t >> 6, lane = t & 63;
  if (lane == 0) { sb[wave] = s; sb[4 + wave] = ss; }
  __syncthreads();
  s = sb[0] + sb[1] + sb[2] + sb[3];
  ss = sb[4] + sb[5] + sb[6] + sb[7];
  float mu = s / (float)DM_;
  float var = ss / (float)DM_ - mu * mu;
  float rs = rsqrtf(var + 1e-5f);
  Y[(size_t)row * DM_ + t]       = f2bf((v0 - mu) * rs * g[t]       + b[t]);
  Y[(size_t)row * DM_ + t + 256] = f2bf((v1 - mu) * rs * g[t + 256] + b[t + 256]);
}

// ---------------------------------------------------------------------------
// Depthwise causal conv (DC=4 taps) + bias + silu.  reverse=1: flipped taps
// (equivalent to conv on the reversed sequence, output in original coords).
// ---------------------------------------------------------------------------
__global__ __launch_bounds__(256)
void conv_k(const short* __restrict__ xz, const float* __restrict__ w,
            const float* __restrict__ cb, short* __restrict__ xc, int reverse)
{
  int idx = blockIdx.x * 256 + threadIdx.x;   // over B*S*DI
  int i = idx & (DI_ - 1);
  int bs = idx >> 10;                         // b*S + t
  int tt0 = bs & (S_ - 1);
  int b = bs >> 9;
  const short* u = xz + (size_t)b * S_ * (2 * DI_) + i;   // row stride 2*DI
  float acc = cb[i];
  #pragma unroll
  for (int k = 0; k < DC_; k++) {
    int tt = reverse ? (tt0 + (DC_ - 1) - k) : (tt0 - (DC_ - 1) + k);
    if (tt >= 0 && tt < S_)
      acc += w[i * DC_ + k] * bf2f(u[(size_t)tt * (2 * DI_)]);
  }
  float sig = 1.f / (1.f + __expf(-acc));
  xc[idx] = f2bf(acc * sig);
}

// ---------------------------------------------------------------------------
// Selective scan. Thread -> (b, i, n). 16-lane shuffle reduce for y.
// Fused epilogue: y = (ys + xc*D) * silu(z).
// ---------------------------------------------------------------------------
__global__ __launch_bounds__(256)
void scan_k(const float* __restrict__ dt, const short* __restrict__ xc,
            const short* __restrict__ xdbl, const short* __restrict__ xz,
            const float* __restrict__ A_log, const float* __restrict__ Dp,
            short* __restrict__ y, int reverse)
{
  const int t = threadIdx.x;
  const int n = t & 15;
  const int b = blockIdx.x >> 6;
  const int i = ((blockIdx.x & 63) << 4) + (t >> 4);
  const float Ai = -__expf(A_log[i * DS_ + n]);
  const float Di = Dp[i];
  float h = 0.f;
  for (int s = 0; s < S_; s++) {
    const int ti = reverse ? (S_ - 1 - s) : s;
    const size_t base = (size_t)b * S_ + ti;
    float dtv = dt[base * DI_ + i];
    float u = bf2f(xc[base * DI_ + i]);
    float Bv = bf2f(xdbl[(base << 6) + DTR_ + n]);
    float Cv = bf2f(xdbl[(base << 6) + DTR_ + DS_ + n]);
    h = __expf(dtv * Ai) * h + (dtv * u) * Bv;
    float p = h * Cv;
    p += __shfl_xor(p, 1);
    p += __shfl_xor(p, 2);
    p += __shfl_xor(p, 4);
    p += __shfl_xor(p, 8);
    if (n == 0) {
      float zv = bf2f(xz[(base << 11) + DI_ + i]);
      float sil = zv / (1.f + __expf(-zv));
      y[base * DI_ + i] = f2bf((p + u * Di) * sil);
    }
  }
}

// ---------------------------------------------------------------------------
// bf16 MFMA GEMM: C[M,N] = A[M,K] * W[N,K]^T, fp32 accum.
// A is bf16 (internal intermediate); W is fp32 (model input), converted to
// bf16 during LDS staging. 128x128 tile, BK=32, 4 waves (2x2), each wave
// 64x64 = 4x4 MFMA 16x16x32. M multiple of 128 (always 4096 here);
// N arbitrary (rows clamped, stores guarded); K multiple of 32.
// ---------------------------------------------------------------------------
enum { EPI_F32_BIAS, EPI_BF16, EPI_F32_SOFTPLUS, EPI_ADD_HALF, EPI_GELU,
       EPI_ADD_BIAS, EPI_PROJ };

__device__ __forceinline__ bf16x8 cvt8(float4 a, float4 b) {
  bf16x8 r;
  r[0] = f2bf(a.x); r[1] = f2bf(a.y); r[2] = f2bf(a.z); r[3] = f2bf(a.w);
  r[4] = f2bf(b.x); r[5] = f2bf(b.y); r[6] = f2bf(b.z); r[7] = f2bf(b.w);
  return r;
}

template <int EPI>
__global__ __launch_bounds__(256)
void gemm_k(const short* __restrict__ A, const float* __restrict__ W,
            int N, int K, int lda, int ldw,
            float* __restrict__ Cf, short* __restrict__ Cb, int ldc,
            const float* __restrict__ bias,
            const float* __restrict__ xlast, const float* __restrict__ stdev,
            const float* __restrict__ means)
{
  __shared__ __align__(16) short As[128 * 32];
  __shared__ __align__(16) short Ws[128 * 32];
  const int tid = threadIdx.x;
  const int m0 = blockIdx.y * 128;
  const int n0 = blockIdx.x * 128;
  const int wave = tid >> 6, lane = tid & 63;
  const int wm = (wave & 1) << 6, wn = (wave >> 1) << 6;
  const int quad = lane >> 4, l16 = lane & 15;
  const int sr = tid >> 2;            // staging row 0..63
  const int sc = (tid & 3) << 3;      // staging k-offset (elements)

  f32x4 acc[4][4] = {};

  int wr0 = n0 + sr;      if (wr0 > N - 1) wr0 = N - 1;
  int wr1 = n0 + sr + 64; if (wr1 > N - 1) wr1 = N - 1;
  const size_t arow0 = (size_t)(m0 + sr) * lda + sc;
  const size_t arow1 = (size_t)(m0 + sr + 64) * lda + sc;
  const size_t wrow0 = (size_t)wr0 * ldw + sc;
  const size_t wrow1 = (size_t)wr1 * ldw + sc;

  for (int k0 = 0; k0 < K; k0 += 32) {
    int4 av0 = *(const int4*)(A + arow0 + k0);
    int4 av1 = *(const int4*)(A + arow1 + k0);
    float4 w00 = *(const float4*)(W + wrow0 + k0);
    float4 w01 = *(const float4*)(W + wrow0 + k0 + 4);
    float4 w10 = *(const float4*)(W + wrow1 + k0);
    float4 w11 = *(const float4*)(W + wrow1 + k0 + 4);
    __syncthreads();
    *(int4*)(As + sr * 32 + sc) = av0;
    *(int4*)(As + (sr + 64) * 32 + sc) = av1;
    *(bf16x8*)(Ws + sr * 32 + sc) = cvt8(w00, w01);
    *(bf16x8*)(Ws + (sr + 64) * 32 + sc) = cvt8(w10, w11);
    __syncthreads();
    bf16x8 af[4], bfr[4];
    #pragma unroll
    for (int mt = 0; mt < 4; mt++)
      af[mt] = *(const bf16x8*)(As + (wm + mt * 16 + l16) * 32 + (quad << 3));
    #pragma unroll
    for (int nt = 0; nt < 4; nt++)
      bfr[nt] = *(const bf16x8*)(Ws + (wn + nt * 16 + l16) * 32 + (quad << 3));
    #pragma unroll
    for (int mt = 0; mt < 4; mt++)
      #pragma unroll
      for (int nt = 0; nt < 4; nt++)
        acc[mt][nt] = __builtin_amdgcn_mfma_f32_16x16x32_bf16(af[mt], bfr[nt], acc[mt][nt], 0, 0, 0);
  }

  #pragma unroll
  for (int mt = 0; mt < 4; mt++) {
    #pragma unroll
    for (int nt = 0; nt < 4; nt++) {
      int n = n0 + wn + nt * 16 + l16;
      if (n >= N) continue;
      #pragma unroll
      for (int r = 0; r < 4; r++) {
        int m = m0 + wm + mt * 16 + quad * 4 + r;
        float v = acc[mt][nt][r];
        if constexpr (EPI == EPI_F32_BIAS) {
          Cf[(size_t)m * ldc + n] = v + bias[n];
        } else if constexpr (EPI == EPI_BF16) {
          Cb[(size_t)m * ldc + n] = f2bf(v);
        } else if constexpr (EPI == EPI_F32_SOFTPLUS) {
          float tt = v + bias[n];
          Cf[(size_t)m * ldc + n] = (tt > 20.f) ? tt : log1pf(__expf(tt));
        } else if constexpr (EPI == EPI_ADD_HALF) {
          Cf[(size_t)m * ldc + n] += 0.5f * v;
        } else if constexpr (EPI == EPI_GELU) {
          float tt = v + bias[n];
          Cb[(size_t)m * ldc + n] = f2bf(0.5f * tt * (1.f + erff(tt * 0.70710678118f)));
        } else if constexpr (EPI == EPI_ADD_BIAS) {
          Cf[(size_t)m * ldc + n] += v + bias[n];
        } else if constexpr (EPI == EPI_PROJ) {
          int bb = m >> 9, d = m & 511;
          float tt = v + bias[n] + xlast[m];
          tt = tt * stdev[m] + means[m];
          Cf[((size_t)bb * PL_ + n) * DV_ + d] = tt;
        }
      }
    }
  }
}

// ---------------------------------------------------------------------------
extern "C" void kernel_launch(void* const* d_in, const int* in_sizes, int n_in,
                              void* d_out, int out_size, void* d_ws, size_t ws_size,
                              hipStream_t stream)
{
  (void)in_sizes; (void)n_in; (void)out_size; (void)ws_size;
  const float* x        = (const float*)d_in[0];
  const float* emb_w    = (const float*)d_in[1];
  const float* emb_b    = (const float*)d_in[2];
  const float* ln_g     = (const float*)d_in[3];
  const float* ln_b     = (const float*)d_in[4];
  const float* m_in_w   = (const float*)d_in[5];
  const float* m_conv_w = (const float*)d_in[6];
  const float* m_conv_b = (const float*)d_in[7];
  const float* m_xp_w   = (const float*)d_in[8];
  const float* m_dt_w   = (const float*)d_in[9];
  const float* m_dt_b   = (const float*)d_in[10];
  const float* m_A_log  = (const float*)d_in[11];
  const float* m_D      = (const float*)d_in[12];
  const float* m_out_w  = (const float*)d_in[13];
  const float* ffn_ln_g = (const float*)d_in[14];
  const float* ffn_ln_b = (const float*)d_in[15];
  const float* ffn_w1   = (const float*)d_in[16];
  const float* ffn_b1   = (const float*)d_in[17];
  const float* ffn_w2   = (const float*)d_in[18];
  const float* ffn_b2   = (const float*)d_in[19];
  const float* enc_g    = (const float*)d_in[20];
  const float* enc_b    = (const float*)d_in[21];
  const float* proj_w   = (const float*)d_in[22];
  const float* proj_b   = (const float*)d_in[23];
  float* out = (float*)d_out;

  char* ws = (char*)d_ws;
  const size_t MB = 1024 * 1024;
  float* h     = (float*)(ws + 0);        //  8 MB  (4096 x 512 fp32)
  short* hn    = (short*)(ws + 8 * MB);   //  4 MB  (4096 x 512 bf16)
  short* xz    = (short*)(ws + 12 * MB);  // 16 MB  (4096 x 2048 bf16) also FFN hidden
  short* xc    = (short*)(ws + 28 * MB);  //  8 MB  (4096 x 1024 bf16)
  short* xdbl  = (short*)(ws + 36 * MB);  // .5 MB  (4096 x 64 bf16)
  float* dtb   = (float*)(ws + 37 * MB);  // 16 MB  (4096 x 1024 fp32)
  short* yact  = (short*)(ws + 53 * MB);  //  8 MB  (4096 x 1024 bf16); xnT aliases
  short* xnT   = (short*)(ws + 53 * MB);  //  4 MB  (4096 x 512 bf16), pre-layer only
  float* stats = (float*)(ws + 61 * MB);  // 64 KB
  float* means = stats, *stdevp = stats + 4096, *rstd = stats + 8192, *xlast = stats + 12288;

  dim3 blk(256);

  stats_k<<<dim3(2, B_), blk, 0, stream>>>(x, means, stdevp, rstd, xlast);
  tnorm_k<<<dim3(8, 8, B_), blk, 0, stream>>>(x, means, rstd, xnT);
  // h[bd,m] = xnT[bd,:] . emb_w[m,:] + emb_b
  gemm_k<EPI_F32_BIAS><<<dim3(4, 32), blk, 0, stream>>>(
      xnT, emb_w, DM_, L_, L_, L_, h, nullptr, DM_, emb_b, nullptr, nullptr, nullptr);

  for (int il = 0; il < EL_; il++) {
    ln_k<<<dim3(4096), blk, 0, stream>>>(h, ln_g + il * DM_, ln_b + il * DM_, hn);
    for (int dir = 0; dir < 2; dir++) {
      int mod = 2 * il + dir;
      gemm_k<EPI_BF16><<<dim3(16, 32), blk, 0, stream>>>(
          hn, m_in_w + (size_t)mod * 2 * DI_ * DM_, 2 * DI_, DM_, DM_, DM_,
          nullptr, xz, 2 * DI_, nullptr, nullptr, nullptr, nullptr);
      conv_k<<<dim3(16384), blk, 0, stream>>>(
          xz, m_conv_w + (size_t)mod * DI_ * DC_, m_conv_b + (size_t)mod * DI_, xc, dir);
      gemm_k<EPI_BF16><<<dim3(1, 32), blk, 0, stream>>>(
          xc, m_xp_w + (size_t)mod * (DTR_ + 2 * DS_) * DI_, DTR_ + 2 * DS_, DI_, DI_, DI_,
          nullptr, xdbl, DTR_ + 2 * DS_, nullptr, nullptr, nullptr, nullptr);
      gemm_k<EPI_F32_SOFTPLUS><<<dim3(8, 32), blk, 0, stream>>>(
          xdbl, m_dt_w + (size_t)mod * DI_ * DTR_, DI_, DTR_, DTR_ + 2 * DS_, DTR_,
          dtb, nullptr, DI_, m_dt_b + (size_t)mod * DI_, nullptr, nullptr, nullptr);
      scan_k<<<dim3(512), blk, 0, stream>>>(
          dtb, xc, xdbl, xz, m_A_log + (size_t)mod * DI_ * DS_, m_D + (size_t)mod * DI_,
          yact, dir);
      gemm_k<EPI_ADD_HALF><<<dim3(4, 32), blk, 0, stream>>>(
          yact, m_out_w + (size_t)mod * DM_ * DI_, DM_, DI_, DI_, DI_,
          h, nullptr, DM_, nullptr, nullptr, nullptr, nullptr);
    }
    ln_k<<<dim3(4096), blk, 0, stream>>>(h, ffn_ln_g + il * DM_, ffn_ln_b + il * DM_, hn);
    gemm_k<EPI_GELU><<<dim3(16, 32), blk, 0, stream>>>(
        hn, ffn_w1 + (size_t)il * 4 * DM_ * DM_, 4 * DM_, DM_, DM_, DM_,
        nullptr, xz, 4 * DM_, ffn_b1 + (size_t)il * 4 * DM_, nullptr, nullptr, nullptr);
    gemm_k<EPI_ADD_BIAS><<<dim3(4, 32), blk, 0, stream>>>(
        xz, ffn_w2 + (size_t)il * DM_ * 4 * DM_, DM_, 4 * DM_, 4 * DM_, 4 * DM_,
        h, nullptr, DM_, ffn_b2 + (size_t)il * DM_, nullptr, nullptr, nullptr);
  }

  ln_k<<<dim3(4096), blk, 0, stream>>>(h, enc_g, enc_b, hn);
  gemm_k<EPI_PROJ><<<dim3(1, 32), blk, 0, stream>>>(
      hn, proj_w, PL_, DM_, DM_, DM_, out, nullptr, 0, proj_b, xlast, stdevp, means);
}

// Round 3
// 2356.678 us; speedup vs baseline: 1.6365x; 1.6365x over previous
//
#include <hip/hip_runtime.h>
#include <math.h>

#define B_ 8
#define L_ 512
#define DV_ 512
#define DM_ 512
#define PL_ 96
#define EL_ 3
#define DS_ 16
#define DC_ 4
#define DI_ 1024
#define DTR_ 32
#define S_ 512
#define CH_ 8          // scan chunks
#define CS_ 64         // steps per chunk

typedef float f32x4 __attribute__((ext_vector_type(4)));
typedef short bf16x8 __attribute__((ext_vector_type(8)));

__device__ __forceinline__ float bf2f(short s) {
  unsigned u = ((unsigned)(unsigned short)s) << 16;
  return __builtin_bit_cast(float, u);
}
__device__ __forceinline__ short f2bf(float f) {
  unsigned u = __builtin_bit_cast(unsigned, f);
  u = u + 0x7FFFu + ((u >> 16) & 1u);   // RNE
  return (short)(u >> 16);
}
__device__ __forceinline__ float h2f(unsigned short u) {
  _Float16 h = __builtin_bit_cast(_Float16, u);
  return (float)h;
}
__device__ __forceinline__ unsigned short f2h(float f) {
  _Float16 h = (_Float16)f;
  return __builtin_bit_cast(unsigned short, h);
}

// ---------------------------------------------------------------------------
// Instance-norm statistics over the time axis (L) of x (B,L,DV) fp32.
// ---------------------------------------------------------------------------
__global__ __launch_bounds__(256)
void stats_k(const float* __restrict__ x, float* __restrict__ means,
             float* __restrict__ stdev, float* __restrict__ rstd,
             float* __restrict__ xlast)
{
  int d = blockIdx.x * 256 + threadIdx.x;       // 0..511
  int b = blockIdx.y;
  const float* xp = x + (size_t)b * L_ * DV_ + d;
  float s = 0.f, ss = 0.f;
  for (int l = 0; l < L_; l++) {
    float v = xp[(size_t)l * DV_];
    s += v; ss += v * v;
  }
  float mu = s / (float)L_;
  float var = ss / (float)L_ - mu * mu;
  float sd = sqrtf(var + 1e-5f);
  float rs = 1.f / sd;
  int idx = b * DV_ + d;
  means[idx] = mu; stdev[idx] = sd; rstd[idx] = rs;
  xlast[idx] = (xp[(size_t)(L_ - 1) * DV_] - mu) * rs;
}

// ---------------------------------------------------------------------------
// Normalize + transpose: xnT[b,d,l] = (x[b,l,d]-mu[b,d])*rstd[b,d]  (bf16)
// ---------------------------------------------------------------------------
__global__ __launch_bounds__(256)
void tnorm_k(const float* __restrict__ x, const float* __restrict__ means,
             const float* __restrict__ rstd, short* __restrict__ xnT)
{
  __shared__ float tile[64][65];
  const int t = threadIdx.x;
  const int j = t & 63;
  const int i0 = t >> 6;                 // 0..3
  const int bz = blockIdx.z;
  const int l0 = blockIdx.y << 6;
  const int d0 = blockIdx.x << 6;
  const float* xp = x + ((size_t)bz * L_ + l0) * DV_ + d0;
  #pragma unroll
  for (int i = i0; i < 64; i += 4) tile[i][j] = xp[(size_t)i * DV_ + j];
  __syncthreads();
  short* op = xnT + ((size_t)bz * DV_ + d0) * L_ + l0;
  const int sb = bz * DV_ + d0;
  #pragma unroll
  for (int i = i0; i < 64; i += 4) {
    float mu = means[sb + i];
    float rs = rstd[sb + i];
    op[(size_t)i * L_ + j] = f2bf((tile[j][i] - mu) * rs);
  }
}

// ---------------------------------------------------------------------------
// LayerNorm over last dim (512) of fp32 h -> bf16 out.  One block per row.
// ---------------------------------------------------------------------------
__global__ __launch_bounds__(256)
void ln_k(const float* __restrict__ X, const float* __restrict__ g,
          const float* __restrict__ b, short* __restrict__ Y)
{
  int row = blockIdx.x;
  const float* x = X + (size_t)row * DM_;
  int t = threadIdx.x;
  float v0 = x[t], v1 = x[t + 256];
  float s = v0 + v1, ss = v0 * v0 + v1 * v1;
  #pragma unroll
  for (int o = 1; o < 64; o <<= 1) { s += __shfl_xor(s, o); ss += __shfl_xor(ss, o); }
  __shared__ float sb[8];
  int wave = t >> 6, lane = t & 63;
  if (lane == 0) { sb[wave] = s; sb[4 + wave] = ss; }
  __syncthreads();
  s = sb[0] + sb[1] + sb[2] + sb[3];
  ss = sb[4] + sb[5] + sb[6] + sb[7];
  float mu = s / (float)DM_;
  float var = ss / (float)DM_ - mu * mu;
  float rs = rsqrtf(var + 1e-5f);
  Y[(size_t)row * DM_ + t]       = f2bf((v0 - mu) * rs * g[t]       + b[t]);
  Y[(size_t)row * DM_ + t + 256] = f2bf((v1 - mu) * rs * g[t + 256] + b[t + 256]);
}

// ---------------------------------------------------------------------------
// Depthwise causal conv (DC=4 taps) + bias + silu.
// ---------------------------------------------------------------------------
__global__ __launch_bounds__(256)
void conv_k(const short* __restrict__ xz, const float* __restrict__ w,
            const float* __restrict__ cb, short* __restrict__ xc, int reverse)
{
  int idx = blockIdx.x * 256 + threadIdx.x;   // over B*S*DI
  int i = idx & (DI_ - 1);
  int bs = idx >> 10;                         // b*S + t
  int tt0 = bs & (S_ - 1);
  int b = bs >> 9;
  const short* u = xz + (size_t)b * S_ * (2 * DI_) + i;   // row stride 2*DI
  float acc = cb[i];
  #pragma unroll
  for (int k = 0; k < DC_; k++) {
    int tt = reverse ? (tt0 + (DC_ - 1) - k) : (tt0 - (DC_ - 1) + k);
    if (tt >= 0 && tt < S_)
      acc += w[i * DC_ + k] * bf2f(u[(size_t)tt * (2 * DI_)]);
  }
  float sig = 1.f / (1.f + __expf(-acc));
  xc[idx] = f2bf(acc * sig);
}

// ---------------------------------------------------------------------------
// Chunked selective scan.  Thread -> (b, i, n); blockIdx.y = chunk (64 steps).
// P1: per-chunk local state + prod(dA).  P2: sequential inter-chunk combine.
// P3: recompute with correct incoming state, emit y with silu(z) epilogue.
// part layout: [(c*B + b)*DI + i]*16 + n
// ---------------------------------------------------------------------------
__global__ __launch_bounds__(256)
void scan_p1(const unsigned short* __restrict__ dt16, const short* __restrict__ xc,
             const short* __restrict__ xdbl, const float* __restrict__ A_log,
             float* __restrict__ part_h, float* __restrict__ part_A, int reverse)
{
  const int t = threadIdx.x;
  const int n = t & 15;
  const int b = blockIdx.x >> 6;
  const int i = ((blockIdx.x & 63) << 4) + (t >> 4);
  const int c = blockIdx.y;
  const float Ai = -__expf(A_log[i * DS_ + n]);
  float hl = 0.f, pA = 1.f;
  #pragma unroll 4
  for (int sl = 0; sl < CS_; sl++) {
    const int s = c * CS_ + sl;
    const int ti = reverse ? (S_ - 1 - s) : s;
    const size_t base = (size_t)b * S_ + ti;
    float dtv = h2f(dt16[base * DI_ + i]);
    float u = bf2f(xc[base * DI_ + i]);
    float Bv = bf2f(xdbl[(base << 6) + DTR_ + n]);
    float dA = __expf(dtv * Ai);
    hl = dA * hl + (dtv * u) * Bv;
    pA *= dA;
  }
  const size_t ix = ((((size_t)c * B_ + b) * DI_ + i) << 4) + n;
  part_h[ix] = hl;
  part_A[ix] = pA;
}

__global__ __launch_bounds__(256)
void scan_p2(float* __restrict__ part_h, const float* __restrict__ part_A)
{
  const size_t gid = (size_t)blockIdx.x * 256 + threadIdx.x;   // B*DI*DS
  const size_t stride = (size_t)B_ * DI_ * DS_;
  float hin = 0.f;
  #pragma unroll
  for (int c = 0; c < CH_; c++) {
    size_t ix = (size_t)c * stride + gid;
    float hh = part_h[ix];
    float pA = part_A[ix];
    part_h[ix] = hin;            // becomes chunk c's incoming state
    hin = hh + pA * hin;
  }
}

__global__ __launch_bounds__(256)
void scan_p3(const unsigned short* __restrict__ dt16, const short* __restrict__ xc,
             const short* __restrict__ xdbl, const short* __restrict__ xz,
             const float* __restrict__ A_log, const float* __restrict__ Dp,
             const float* __restrict__ part_h, short* __restrict__ y, int reverse)
{
  const int t = threadIdx.x;
  const int n = t & 15;
  const int b = blockIdx.x >> 6;
  const int i = ((blockIdx.x & 63) << 4) + (t >> 4);
  const int c = blockIdx.y;
  const float Ai = -__expf(A_log[i * DS_ + n]);
  const float Di = Dp[i];
  float h = part_h[((((size_t)c * B_ + b) * DI_ + i) << 4) + n];
  #pragma unroll 4
  for (int sl = 0; sl < CS_; sl++) {
    const int s = c * CS_ + sl;
    const int ti = reverse ? (S_ - 1 - s) : s;
    const size_t base = (size_t)b * S_ + ti;
    float dtv = h2f(dt16[base * DI_ + i]);
    float u = bf2f(xc[base * DI_ + i]);
    float Bv = bf2f(xdbl[(base << 6) + DTR_ + n]);
    float Cv = bf2f(xdbl[(base << 6) + DTR_ + DS_ + n]);
    h = __expf(dtv * Ai) * h + (dtv * u) * Bv;
    float p = h * Cv;
    p += __shfl_xor(p, 1);
    p += __shfl_xor(p, 2);
    p += __shfl_xor(p, 4);
    p += __shfl_xor(p, 8);
    if (n == 0) {
      float zv = bf2f(xz[(base << 11) + DI_ + i]);
      float sil = zv / (1.f + __expf(-zv));
      y[base * DI_ + i] = f2bf((p + u * Di) * sil);
    }
  }
}

// ---------------------------------------------------------------------------
// bf16 MFMA GEMM: C[M,N] = A[M,K] * W[N,K]^T, fp32 accum.  A bf16 internal;
// W fp32 input converted during LDS staging.  128x128 tile, BK=32.
// ---------------------------------------------------------------------------
enum { EPI_F32_BIAS, EPI_BF16, EPI_F16_SOFTPLUS, EPI_ADD_HALF, EPI_GELU,
       EPI_ADD_BIAS, EPI_PROJ };

__device__ __forceinline__ bf16x8 cvt8(float4 a, float4 b) {
  bf16x8 r;
  r[0] = f2bf(a.x); r[1] = f2bf(a.y); r[2] = f2bf(a.z); r[3] = f2bf(a.w);
  r[4] = f2bf(b.x); r[5] = f2bf(b.y); r[6] = f2bf(b.z); r[7] = f2bf(b.w);
  return r;
}

template <int EPI>
__global__ __launch_bounds__(256)
void gemm_k(const short* __restrict__ A, const float* __restrict__ W,
            int N, int K, int lda, int ldw,
            float* __restrict__ Cf, short* __restrict__ Cb, int ldc,
            const float* __restrict__ bias,
            const float* __restrict__ xlast, const float* __restrict__ stdev,
            const float* __restrict__ means)
{
  __shared__ __align__(16) short As[128 * 32];
  __shared__ __align__(16) short Ws[128 * 32];
  const int tid = threadIdx.x;
  const int m0 = blockIdx.y * 128;
  const int n0 = blockIdx.x * 128;
  const int wave = tid >> 6, lane = tid & 63;
  const int wm = (wave & 1) << 6, wn = (wave >> 1) << 6;
  const int quad = lane >> 4, l16 = lane & 15;
  const int sr = tid >> 2;            // staging row 0..63
  const int sc = (tid & 3) << 3;      // staging k-offset (elements)

  f32x4 acc[4][4] = {};

  int wr0 = n0 + sr;      if (wr0 > N - 1) wr0 = N - 1;
  int wr1 = n0 + sr + 64; if (wr1 > N - 1) wr1 = N - 1;
  const size_t arow0 = (size_t)(m0 + sr) * lda + sc;
  const size_t arow1 = (size_t)(m0 + sr + 64) * lda + sc;
  const size_t wrow0 = (size_t)wr0 * ldw + sc;
  const size_t wrow1 = (size_t)wr1 * ldw + sc;

  for (int k0 = 0; k0 < K; k0 += 32) {
    int4 av0 = *(const int4*)(A + arow0 + k0);
    int4 av1 = *(const int4*)(A + arow1 + k0);
    float4 w00 = *(const float4*)(W + wrow0 + k0);
    float4 w01 = *(const float4*)(W + wrow0 + k0 + 4);
    float4 w10 = *(const float4*)(W + wrow1 + k0);
    float4 w11 = *(const float4*)(W + wrow1 + k0 + 4);
    __syncthreads();
    *(int4*)(As + sr * 32 + sc) = av0;
    *(int4*)(As + (sr + 64) * 32 + sc) = av1;
    *(bf16x8*)(Ws + sr * 32 + sc) = cvt8(w00, w01);
    *(bf16x8*)(Ws + (sr + 64) * 32 + sc) = cvt8(w10, w11);
    __syncthreads();
    bf16x8 af[4], bfr[4];
    #pragma unroll
    for (int mt = 0; mt < 4; mt++)
      af[mt] = *(const bf16x8*)(As + (wm + mt * 16 + l16) * 32 + (quad << 3));
    #pragma unroll
    for (int nt = 0; nt < 4; nt++)
      bfr[nt] = *(const bf16x8*)(Ws + (wn + nt * 16 + l16) * 32 + (quad << 3));
    #pragma unroll
    for (int mt = 0; mt < 4; mt++)
      #pragma unroll
      for (int nt = 0; nt < 4; nt++)
        acc[mt][nt] = __builtin_amdgcn_mfma_f32_16x16x32_bf16(af[mt], bfr[nt], acc[mt][nt], 0, 0, 0);
  }

  #pragma unroll
  for (int mt = 0; mt < 4; mt++) {
    #pragma unroll
    for (int nt = 0; nt < 4; nt++) {
      int n = n0 + wn + nt * 16 + l16;
      if (n >= N) continue;
      #pragma unroll
      for (int r = 0; r < 4; r++) {
        int m = m0 + wm + mt * 16 + quad * 4 + r;
        float v = acc[mt][nt][r];
        if constexpr (EPI == EPI_F32_BIAS) {
          Cf[(size_t)m * ldc + n] = v + bias[n];
        } else if constexpr (EPI == EPI_BF16) {
          Cb[(size_t)m * ldc + n] = f2bf(v);
        } else if constexpr (EPI == EPI_F16_SOFTPLUS) {
          float tt = v + bias[n];
          float sp = (tt > 20.f) ? tt : log1pf(__expf(tt));
          ((unsigned short*)Cb)[(size_t)m * ldc + n] = f2h(sp);
        } else if constexpr (EPI == EPI_ADD_HALF) {
          Cf[(size_t)m * ldc + n] += 0.5f * v;
        } else if constexpr (EPI == EPI_GELU) {
          float tt = v + bias[n];
          Cb[(size_t)m * ldc + n] = f2bf(0.5f * tt * (1.f + erff(tt * 0.70710678118f)));
        } else if constexpr (EPI == EPI_ADD_BIAS) {
          Cf[(size_t)m * ldc + n] += v + bias[n];
        } else if constexpr (EPI == EPI_PROJ) {
          int bb = m >> 9, d = m & 511;
          float tt = v + bias[n] + xlast[m];
          tt = tt * stdev[m] + means[m];
          Cf[((size_t)bb * PL_ + n) * DV_ + d] = tt;
        }
      }
    }
  }
}

// ---------------------------------------------------------------------------
extern "C" void kernel_launch(void* const* d_in, const int* in_sizes, int n_in,
                              void* d_out, int out_size, void* d_ws, size_t ws_size,
                              hipStream_t stream)
{
  (void)in_sizes; (void)n_in; (void)out_size; (void)ws_size;
  const float* x        = (const float*)d_in[0];
  const float* emb_w    = (const float*)d_in[1];
  const float* emb_b    = (const float*)d_in[2];
  const float* ln_g     = (const float*)d_in[3];
  const float* ln_b     = (const float*)d_in[4];
  const float* m_in_w   = (const float*)d_in[5];
  const float* m_conv_w = (const float*)d_in[6];
  const float* m_conv_b = (const float*)d_in[7];
  const float* m_xp_w   = (const float*)d_in[8];
  const float* m_dt_w   = (const float*)d_in[9];
  const float* m_dt_b   = (const float*)d_in[10];
  const float* m_A_log  = (const float*)d_in[11];
  const float* m_D      = (const float*)d_in[12];
  const float* m_out_w  = (const float*)d_in[13];
  const float* ffn_ln_g = (const float*)d_in[14];
  const float* ffn_ln_b = (const float*)d_in[15];
  const float* ffn_w1   = (const float*)d_in[16];
  const float* ffn_b1   = (const float*)d_in[17];
  const float* ffn_w2   = (const float*)d_in[18];
  const float* ffn_b2   = (const float*)d_in[19];
  const float* enc_g    = (const float*)d_in[20];
  const float* enc_b    = (const float*)d_in[21];
  const float* proj_w   = (const float*)d_in[22];
  const float* proj_b   = (const float*)d_in[23];
  float* out = (float*)d_out;

  char* ws = (char*)d_ws;
  const size_t MB = 1024 * 1024;
  float* h      = (float*)(ws + 0);        //  8 MB  (4096 x 512 fp32)
  short* hn     = (short*)(ws + 8 * MB);   //  4 MB  (4096 x 512 bf16)
  short* xz     = (short*)(ws + 12 * MB);  // 16 MB  (4096 x 2048 bf16) also FFN hidden
  short* xc     = (short*)(ws + 28 * MB);  //  8 MB  (4096 x 1024 bf16)
  short* xdbl   = (short*)(ws + 36 * MB);  // .5 MB  (4096 x 64 bf16)
  unsigned short* dtb = (unsigned short*)(ws + 37 * MB); // 8 MB (4096 x 1024 fp16)
  float* part_h = (float*)(ws + 45 * MB);  //  4 MB  (8 x 8 x 1024 x 16 fp32)
  float* part_A = (float*)(ws + 49 * MB);  //  4 MB
  short* yact   = (short*)(ws + 53 * MB);  //  8 MB  (4096 x 1024 bf16); xnT aliases
  short* xnT    = (short*)(ws + 53 * MB);  //  4 MB  pre-layer only
  float* stats  = (float*)(ws + 61 * MB);  // 64 KB
  float* means = stats, *stdevp = stats + 4096, *rstd = stats + 8192, *xlast = stats + 12288;

  dim3 blk(256);

  stats_k<<<dim3(2, B_), blk, 0, stream>>>(x, means, stdevp, rstd, xlast);
  tnorm_k<<<dim3(8, 8, B_), blk, 0, stream>>>(x, means, rstd, xnT);
  gemm_k<EPI_F32_BIAS><<<dim3(4, 32), blk, 0, stream>>>(
      xnT, emb_w, DM_, L_, L_, L_, h, nullptr, DM_, emb_b, nullptr, nullptr, nullptr);

  for (int il = 0; il < EL_; il++) {
    ln_k<<<dim3(4096), blk, 0, stream>>>(h, ln_g + il * DM_, ln_b + il * DM_, hn);
    for (int dir = 0; dir < 2; dir++) {
      int mod = 2 * il + dir;
      gemm_k<EPI_BF16><<<dim3(16, 32), blk, 0, stream>>>(
          hn, m_in_w + (size_t)mod * 2 * DI_ * DM_, 2 * DI_, DM_, DM_, DM_,
          nullptr, xz, 2 * DI_, nullptr, nullptr, nullptr, nullptr);
      conv_k<<<dim3(16384), blk, 0, stream>>>(
          xz, m_conv_w + (size_t)mod * DI_ * DC_, m_conv_b + (size_t)mod * DI_, xc, dir);
      gemm_k<EPI_BF16><<<dim3(1, 32), blk, 0, stream>>>(
          xc, m_xp_w + (size_t)mod * (DTR_ + 2 * DS_) * DI_, DTR_ + 2 * DS_, DI_, DI_, DI_,
          nullptr, xdbl, DTR_ + 2 * DS_, nullptr, nullptr, nullptr, nullptr);
      gemm_k<EPI_F16_SOFTPLUS><<<dim3(8, 32), blk, 0, stream>>>(
          xdbl, m_dt_w + (size_t)mod * DI_ * DTR_, DI_, DTR_, DTR_ + 2 * DS_, DTR_,
          nullptr, (short*)dtb, DI_, m_dt_b + (size_t)mod * DI_, nullptr, nullptr, nullptr);
      scan_p1<<<dim3(512, CH_), blk, 0, stream>>>(
          dtb, xc, xdbl, m_A_log + (size_t)mod * DI_ * DS_, part_h, part_A, dir);
      scan_p2<<<dim3(512), blk, 0, stream>>>(part_h, part_A);
      scan_p3<<<dim3(512, CH_), blk, 0, stream>>>(
          dtb, xc, xdbl, xz, m_A_log + (size_t)mod * DI_ * DS_, m_D + (size_t)mod * DI_,
          part_h, yact, dir);
      gemm_k<EPI_ADD_HALF><<<dim3(4, 32), blk, 0, stream>>>(
          yact, m_out_w + (size_t)mod * DM_ * DI_, DM_, DI_, DI_, DI_,
          h, nullptr, DM_, nullptr, nullptr, nullptr, nullptr);
    }
    ln_k<<<dim3(4096), blk, 0, stream>>>(h, ffn_ln_g + il * DM_, ffn_ln_b + il * DM_, hn);
    gemm_k<EPI_GELU><<<dim3(16, 32), blk, 0, stream>>>(
        hn, ffn_w1 + (size_t)il * 4 * DM_ * DM_, 4 * DM_, DM_, DM_, DM_,
        nullptr, xz, 4 * DM_, ffn_b1 + (size_t)il * 4 * DM_, nullptr, nullptr, nullptr);
    gemm_k<EPI_ADD_BIAS><<<dim3(4, 32), blk, 0, stream>>>(
        xz, ffn_w2 + (size_t)il * DM_ * 4 * DM_, DM_, 4 * DM_, 4 * DM_, 4 * DM_,
        h, nullptr, DM_, ffn_b2 + (size_t)il * DM_, nullptr, nullptr, nullptr);
  }

  ln_k<<<dim3(4096), blk, 0, stream>>>(h, enc_g, enc_b, hn);
  gemm_k<EPI_PROJ><<<dim3(1, 32), blk, 0, stream>>>(
      hn, proj_w, PL_, DM_, DM_, DM_, out, nullptr, 0, proj_b, xlast, stdevp, means);
}